// Round 4
// baseline (72.389 us; speedup 1.0000x reference)
//
#include <hip/hip_runtime.h>
#include <math.h>

#define DIM 160
#define HT 16
#define ROWS (HT + 6)          // 22 staged rows (h-halo)
#define LROW 168               // 4 zero-pad | 160 data | 4 zero-pad
#define LROW4 (LROW / 4)       // 42 float4 per padded row
#define CHUNK 8                // output d-slices per block
#define NSTEP (CHUNK + 6)      // 14 WH-slice steps (d-halo)
#define THREADS 320
#define SLICE4 (ROWS * 40)     // 880 float4 W-blur outputs per slice
#define STAGE4 (ROWS * LROW4)  // 924 float4 staged per slice

struct W7 { float w[7]; };

__global__ __launch_bounds__(THREADS) void blur3d_fused(
    const float* __restrict__ in, float* __restrict__ out, W7 wt) {
    __shared__ float inL[ROWS * LROW];   // raw rows of current input slice (14.8 KB)
    __shared__ float tmpL[ROWS * DIM];   // W-blurred rows                  (14.1 KB)

    const int tilesH = DIM / HT;         // 10
    const int nchunk = DIM / CHUNK;      // 20
    const int b   = blockIdx.x;
    const int nc  = b / (tilesH * nchunk);
    const int rem = b % (tilesH * nchunk);
    const int h0  = (rem / nchunk) * HT;
    const int d0  = (rem % nchunk) * CHUNK;
    const int tid = threadIdx.x;

    const float* src = in  + (size_t)nc * (DIM * DIM * DIM);
    float*       dst = out + (size_t)nc * (DIM * DIM * DIM);

    const int hh = tid / 40;   // 0..7  (owns rows hh, hh+8 of the tile)
    const int cc = tid % 40;   // float4 column

    float4 win[7][2];          // 7-slice register ring of WH-blurred values
    float4 ld0, ld1, ld2;      // in-flight staging registers (T14 split)

    // ---- issue global loads for slice d into regs (zero outside range) ----
    auto stage_load = [&](int d) {
        ld0 = ld1 = ld2 = make_float4(0.f, 0.f, 0.f, 0.f);
        if ((unsigned)d < DIM) {
            const float* sl = src + (size_t)d * (DIM * DIM);
            {
                int i = tid;
                int r = i / LROW4, q = i % LROW4, h = h0 - 3 + r;
                if (q >= 1 && q <= 40 && (unsigned)h < DIM)
                    ld0 = ((const float4*)(sl + h * DIM))[q - 1];
            }
            {
                int i = tid + THREADS;
                int r = i / LROW4, q = i % LROW4, h = h0 - 3 + r;
                if (q >= 1 && q <= 40 && (unsigned)h < DIM)
                    ld1 = ((const float4*)(sl + h * DIM))[q - 1];
            }
            {
                int i = tid + 2 * THREADS;
                if (i < STAGE4) {
                    int r = i / LROW4, q = i % LROW4, h = h0 - 3 + r;
                    if (q >= 1 && q <= 40 && (unsigned)h < DIM)
                        ld2 = ((const float4*)(sl + h * DIM))[q - 1];
                }
            }
        }
    };
    // ---- commit staged regs to LDS (compiler inserts vmcnt wait here) ----
    auto stage_write = [&]() {
        ((float4*)inL)[tid]           = ld0;
        ((float4*)inL)[tid + THREADS] = ld1;
        if (tid + 2 * THREADS < STAGE4) ((float4*)inL)[tid + 2 * THREADS] = ld2;
    };
    // ---- W-blur staged slice: inL -> tmpL (branch-free, guard pads) ----
    auto wblur = [&]() {
#pragma unroll
        for (int p = 0; p < 3; ++p) {
            int i = tid + p * THREADS;
            if (i < SLICE4) {
                int r = i / 40, c = i % 40;
                const float4* row = (const float4*)(inL + r * LROW);
                float4 v0 = row[c], v1 = row[c + 1], v2 = row[c + 2];
                float f1 = v0.y, f2 = v0.z, f3 = v0.w;
                float f4 = v1.x, f5 = v1.y, f6 = v1.z, f7 = v1.w;
                float f8 = v2.x, f9 = v2.y, f10 = v2.z;
                float4 o;
                o.x = wt.w[0]*f1 + wt.w[1]*f2 + wt.w[2]*f3 + wt.w[3]*f4
                    + wt.w[4]*f5 + wt.w[5]*f6 + wt.w[6]*f7;
                o.y = wt.w[0]*f2 + wt.w[1]*f3 + wt.w[2]*f4 + wt.w[3]*f5
                    + wt.w[4]*f6 + wt.w[5]*f7 + wt.w[6]*f8;
                o.z = wt.w[0]*f3 + wt.w[1]*f4 + wt.w[2]*f5 + wt.w[3]*f6
                    + wt.w[4]*f7 + wt.w[5]*f8 + wt.w[6]*f9;
                o.w = wt.w[0]*f4 + wt.w[1]*f5 + wt.w[2]*f6 + wt.w[3]*f7
                    + wt.w[4]*f8 + wt.w[5]*f9 + wt.w[6]*f10;
                ((float4*)(tmpL + r * DIM))[c] = o;
            }
        }
    };
    // ---- H-blur thread's two rows from tmpL into a ring slot ----
    auto hblur = [&](float4* slot) {
#pragma unroll
        for (int r2 = 0; r2 < 2; ++r2) {
            const float* base = tmpL + (hh + r2 * 8) * DIM;
            float4 a = make_float4(0.f, 0.f, 0.f, 0.f);
#pragma unroll
            for (int j = 0; j < 7; ++j) {
                float4 t4 = ((const float4*)(base + j * DIM))[cc];
                float wj = wt.w[j];
                a.x += wj * t4.x; a.y += wj * t4.y;
                a.z += wj * t4.z; a.w += wj * t4.w;
            }
            slot[r2] = a;
        }
    };

    // ---- prologue: stage first slice (d0-3) ----
    stage_load(d0 - 3);
    stage_write();
    __syncthreads();

    // ---- main march: 14 steps = 2 x 7 (ring indices static in u) ----
    for (int it = 0; it < 2; ++it) {
#pragma unroll
        for (int u = 0; u < 7; ++u) {
            const int t = it * 7 + u;          // runtime-uniform
            if (t < NSTEP - 1) stage_load(d0 - 2 + t);   // issue next slice
            wblur();                           // inL (slice d0-3+t) -> tmpL
            __syncthreads();                   // tmpL ready
            hblur(win[u]);                     // slot t%7 == u
            if (t >= 6) {
                int d = d0 + t - 6;
                float* orow = dst + (size_t)d * (DIM * DIM) + (size_t)h0 * DIM;
#pragma unroll
                for (int r2 = 0; r2 < 2; ++r2) {
                    float4 o = make_float4(0.f, 0.f, 0.f, 0.f);
#pragma unroll
                    for (int j = 0; j < 7; ++j) {
                        const float4 v = win[(u + 1 + j) % 7][r2];
                        float wj = wt.w[j];
                        o.x += wj * v.x; o.y += wj * v.y;
                        o.z += wj * v.z; o.w += wj * v.w;
                    }
                    ((float4*)(orow + (hh + r2 * 8) * DIM))[cc] = o;
                }
            }
            if (t < NSTEP - 1) stage_write();  // commit next slice to inL
            __syncthreads();                   // inL/tmpL safe to reuse
        }
    }
}

extern "C" void kernel_launch(void* const* d_in, const int* in_sizes, int n_in,
                              void* d_out, int out_size, void* d_ws, size_t ws_size,
                              hipStream_t stream) {
    const float* x = (const float*)d_in[0];
    float* out = (float*)d_out;
    const int total = out_size;                      // 2*2*160^3

    W7 wt;
    double s = 0.0;
    for (int i = 0; i < 7; ++i) {
        double v = exp(-((i - 3) * (i - 3)) / 8.0);
        wt.w[i] = (float)v;
        s += v;
    }
    for (int i = 0; i < 7; ++i) wt.w[i] = (float)(wt.w[i] / s);

    const int nc = total / (DIM * DIM * DIM);        // 4
    const int grid = nc * (DIM / HT) * (DIM / CHUNK);  // 800
    blur3d_fused<<<grid, THREADS, 0, stream>>>(x, out, wt);
}